// Round 7
// baseline (2227.123 us; speedup 1.0000x reference)
//
#include <hip/hip_runtime.h>
#include <hip/hip_bf16.h>

typedef __attribute__((ext_vector_type(8))) short  short8;   // 8 bf16 (4 VGPRs) MFMA frag
typedef __attribute__((ext_vector_type(4))) float  f32x4;    // MFMA accum frag

#define T_TOTAL 512
#define BATCH   64
#define VOCAB   32000
#define EMB     512
#define RNN     1024
#define G3      3072      // 3*RNN
#define WROWS   48        // 3 gates x 16 units per WG
#define WPAD    1032      // w_hh LDS row stride (shorts): 2-way bank alias (free, proven)
#define APAD2   520       // w_ih LDS row stride (shorts): same 2-way alias class
#define RPAD    18        // red[] batch stride (floats): max 2-way (free)
#define NWG     256
#define NGRP    4         // independent batch groups (16 batches each)
#define NLINE   2         // arrival lines per group (32 WGs each)
// LDS: w_hh 48*1032*2=99072 | w_ih 48*520*2=49920 | red 4*48*18*4=13824 -> 162816
#define REC_SMEM (WROWS * WPAD * 2 + WROWS * APAD2 * 2 + 4 * WROWS * RPAD * 4)

// ---- bf16 helpers ----
__device__ __forceinline__ unsigned short f2bf(float f) {
    union { float f; unsigned int u; } v; v.f = f;
    unsigned int r = v.u + 0x7fffu + ((v.u >> 16) & 1u);   // round-nearest-even
    return (unsigned short)(r >> 16);
}
__device__ __forceinline__ float bf2f(unsigned short h) {
    union { unsigned int u; float f; } v; v.u = ((unsigned int)h) << 16;
    return v.f;
}
__device__ __forceinline__ float sigmoidf_(float x) { return 1.f / (1.f + __expf(-x)); }
__device__ __forceinline__ float tanhf_(float x) {
    float ax = fabsf(x);
    float e2 = __expf(-2.f * ax);
    float t  = (1.f - e2) / (1.f + e2);
    return x < 0.f ? -t : t;
}

// ============================================================================
// R0/R7 barrier (best measured, VERBATIM): split-phase per-group.
// Arrive: thread0 RMWs its 32-WG arrival line. Wait: lanes 0/1 poll BOTH
// arrival lines (exec-masked spin until each hits 32*ph).
// ============================================================================
__device__ __forceinline__ void gbar_arrive(unsigned int* lines, int lid,
                                            unsigned int ph) {
    __syncthreads();                         // all waves' h stores drained (vmcnt 0)
    if (threadIdx.x == 0)
        __hip_atomic_fetch_add(&lines[lid * 64], 1u,
                               __ATOMIC_RELAXED, __HIP_MEMORY_SCOPE_AGENT);
}
__device__ __forceinline__ void gbar_wait(unsigned int* lines, unsigned int ph) {
    if (threadIdx.x < NLINE) {               // lanes 0,1 of wave 0, exec-masked spin
        while (__hip_atomic_load(&lines[threadIdx.x * 64], __ATOMIC_RELAXED,
                                 __HIP_MEMORY_SCOPE_AGENT) < ph * 32u)
            __builtin_amdgcn_s_sleep(1);
    }
    __syncthreads();
}

__global__ void bar_init(unsigned int* bar) {
    for (int i = threadIdx.x; i < NGRP * 256; i += 256) bar[i] = 0;
}

// f32 -> bf16 pre-convert (8 elems/thread). One-shot per launch; BW-bound.
__global__ __launch_bounds__(256) void cvt_bf16_kernel(
    const float* __restrict__ s, unsigned short* __restrict__ d, int n8)
{
    const int i = blockIdx.x * 256 + threadIdx.x;
    if (i >= n8) return;
    const float4 a = ((const float4*)s)[i * 2];
    const float4 b = ((const float4*)s)[i * 2 + 1];
    short8 v;
    v[0] = f2bf(a.x); v[1] = f2bf(a.y); v[2] = f2bf(a.z); v[3] = f2bf(a.w);
    v[4] = f2bf(b.x); v[5] = f2bf(b.y); v[6] = f2bf(b.z); v[7] = f2bf(b.w);
    ((short8*)d)[i] = v;
}

// ============================================================================
// K2: recurrence with FUSED gi (no gi kernel, no gi buffer).
// Each WG computes the exact gi slice it consumes: 16 batches x 48 units,
// K=512 against w_ih rows {gate*RNN+j0+u} held resident in LDS (bf16).
// gi(t+1) is computed in the arrive->wait window (idle spin time): per wave
// (k-quarter of 512 = 128): 4 B-frags (gathered emb rows, bf16) x 3 gate
// tiles = 12 MFMAs; partials go to the SAME red[] buffer (time-multiplexed
// with rec partials; +1 syncthreads/step) and are reduced at the top of the
// next step with b_ih added. Everything else is the R0 kernel verbatim.
// ============================================================================
template<bool BF>
__global__ __launch_bounds__(256, 1) void rec_kernel(
    const int* __restrict__ x, const void* __restrict__ embp,
    const float* __restrict__ w_ih, const float* __restrict__ b_ih,
    const float* __restrict__ w_hh, const float* __restrict__ b_hh,
    unsigned short* __restrict__ hb0, unsigned short* __restrict__ hb1,
    float* __restrict__ hf, unsigned int* bar, int t0, int nsteps, int pbase)
{
    extern __shared__ __align__(16) char smem[];
    unsigned short* Wsm = (unsigned short*)smem;                       // 48 x WPAD
    unsigned short* Wih = (unsigned short*)smem + WROWS * WPAD;        // 48 x APAD2
    float (*red)[WROWS][RPAD] =
        (float (*)[WROWS][RPAD])(smem + WROWS * WPAD * 2 + WROWS * APAD2 * 2);

    const int tid = threadIdx.x;
    const int wg  = blockIdx.x;
    const int grp = wg & 3, sidx = wg >> 2;
    const int b0 = grp * 16, j0 = sidx * 16;
    unsigned int* lines = &bar[grp * 256];          // 2 lines, 256B apart
    const int lid = sidx & (NLINE - 1);

    // ---- stage w_hh slice -> LDS bf16 (rows: [gate*16+u][k]) ----
    #pragma unroll 4
    for (int it = 0; it < 48; ++it) {
        const int i   = it * 256 + tid;
        const int row = i >> 8;                     // 0..47 (256 float4 per row)
        const int c4  = (i & 255) * 4;
        const int gate = row >> 4, uu = row & 15;
        const float4 v = *(const float4*)(w_hh + (size_t)(gate * RNN + j0 + uu) * RNN + c4);
        unsigned short* dst = &Wsm[row * WPAD + c4];
        dst[0] = f2bf(v.x); dst[1] = f2bf(v.y); dst[2] = f2bf(v.z); dst[3] = f2bf(v.w);
    }
    // ---- stage w_ih slice -> LDS bf16 (rows: [gate*16+u][k 0..512]) ----
    #pragma unroll 4
    for (int it = 0; it < 24; ++it) {
        const int i   = it * 256 + tid;
        const int row = i >> 7;                     // 0..47 (128 float4 per row)
        const int c4  = (i & 127) * 4;
        const int gate = row >> 4, uu = row & 15;
        const float4 v = *(const float4*)(w_ih + (size_t)(gate * RNN + j0 + uu) * EMB + c4);
        unsigned short* dst = &Wih[row * APAD2 + c4];
        dst[0] = f2bf(v.x); dst[1] = f2bf(v.y); dst[2] = f2bf(v.z); dst[3] = f2bf(v.w);
    }

    // ---- gate-thread identity: (unit u 0..15, batch bl 0..15) ----
    const int u  = tid & 15;
    const int bl = tid >> 4;
    const int j  = j0 + u;
    const int b  = b0 + bl;
    const float bhr  = b_hh[j], bhi  = b_hh[RNN + j], bhn  = b_hh[2 * RNN + j];
    const float bihr = b_ih[j], bihi = b_ih[RNN + j], bihn = b_ih[2 * RNN + j];

    float h_reg;
    if (t0 == 0) {
        h_reg = 0.f;
        if ((u & 1) == 0)
            __hip_atomic_store((unsigned int*)&hb0[b * RNN + j], 0u,
                               __ATOMIC_RELAXED, __HIP_MEMORY_SCOPE_AGENT);
    } else {
        h_reg = hf[b * RNN + j];            // f32 state from previous launch
    }
    gbar_arrive(lines, lid, (unsigned)(pbase + 1));   // syncthreads also covers LDS staging

    // ---- MFMA identity: wave kq = K quarter; lr = batch col / unit row ----
    const int lane = tid & 63, kq = tid >> 6;
    const int lr = lane & 15, lq = lane >> 4;
    const unsigned short* wbase  = Wsm + kq * 256 + lq * 8;           // w_hh: K/4=256
    const unsigned short* wibase = Wih + kq * 128 + lq * 8;           // w_ih: K/4=128
    const size_t hoff = ((size_t)(b0 + lr) * RNN + kq * 256 + lq * 8) >> 2;  // in u64s

    // gi compute for global step tg: partials -> red (same layout as rec)
    auto gi_compute = [&](int tg) {
        const int xi = x[tg * BATCH + b0 + lr];     // gather index for batch col lr
        short8 bfr[4];
        if constexpr (BF) {
            const unsigned short* erow = (const unsigned short*)embp
                                       + (size_t)xi * EMB + kq * 128 + lq * 8;
            #pragma unroll
            for (int ks = 0; ks < 4; ++ks)
                bfr[ks] = *(const short8*)(erow + ks * 32);
        } else {
            const float* erow = (const float*)embp
                              + (size_t)xi * EMB + kq * 128 + lq * 8;
            #pragma unroll
            for (int ks = 0; ks < 4; ++ks) {
                const float4 e0 = *(const float4*)(erow + ks * 32);
                const float4 e1 = *(const float4*)(erow + ks * 32 + 4);
                short8 v;
                v[0]=f2bf(e0.x); v[1]=f2bf(e0.y); v[2]=f2bf(e0.z); v[3]=f2bf(e0.w);
                v[4]=f2bf(e1.x); v[5]=f2bf(e1.y); v[6]=f2bf(e1.z); v[7]=f2bf(e1.w);
                bfr[ks] = v;
            }
        }
        f32x4 acc2[3];
        acc2[0] = (f32x4){0.f, 0.f, 0.f, 0.f};
        acc2[1] = (f32x4){0.f, 0.f, 0.f, 0.f};
        acc2[2] = (f32x4){0.f, 0.f, 0.f, 0.f};
        #pragma unroll
        for (int ks = 0; ks < 4; ++ks)
            #pragma unroll
            for (int gt = 0; gt < 3; ++gt) {
                const short8 a = *(const short8*)(wibase + (gt * 16 + lr) * APAD2 + ks * 32);
                acc2[gt] = __builtin_amdgcn_mfma_f32_16x16x32_bf16(a, bfr[ks],
                                                                   acc2[gt], 0, 0, 0);
            }
        #pragma unroll
        for (int gt = 0; gt < 3; ++gt)
            #pragma unroll
            for (int q = 0; q < 4; ++q)
                red[kq][gt * 16 + lq * 4 + q][lr] = acc2[gt][q];   // row=lq*4+q, col=lr
    };

    // gi(t0) computed under the initial barrier spin window
    gi_compute(t0);
    gbar_wait(lines, (unsigned)(pbase + 1));   // release; red (gi partials) visible

    for (int t = 0; t < nsteps; ++t) {
        // (a) gi-reduce for this step (+ input bias)
        const float gir = red[0][u][bl]      + red[1][u][bl]
                        + red[2][u][bl]      + red[3][u][bl]      + bihr;
        const float gii = red[0][16 + u][bl] + red[1][16 + u][bl]
                        + red[2][16 + u][bl] + red[3][16 + u][bl] + bihi;
        const float gin = red[0][32 + u][bl] + red[1][32 + u][bl]
                        + red[2][32 + u][bl] + red[3][32 + u][bl] + bihn;

        const unsigned short* hrd = (t & 1) ? hb1 : hb0;
        unsigned short*       hwr = (t & 1) ? hb0 : hb1;

        // (b) preload this wave's 16 h u64s (pipelined MALL reads)
        union { unsigned long long q[2]; short8 s8; } hv[8];
        const unsigned long long* hp = (const unsigned long long*)hrd + hoff;
        #pragma unroll
        for (int ks = 0; ks < 8; ++ks) {
            hv[ks].q[0] = __hip_atomic_load(hp + ks * 8,     __ATOMIC_RELAXED,
                                            __HIP_MEMORY_SCOPE_AGENT);
            hv[ks].q[1] = __hip_atomic_load(hp + ks * 8 + 1, __ATOMIC_RELAXED,
                                            __HIP_MEMORY_SCOPE_AGENT);
        }

        // (c) rec MFMAs
        f32x4 acc[3];
        acc[0] = (f32x4){0.f, 0.f, 0.f, 0.f};
        acc[1] = (f32x4){0.f, 0.f, 0.f, 0.f};
        acc[2] = (f32x4){0.f, 0.f, 0.f, 0.f};
        #pragma unroll
        for (int ks = 0; ks < 8; ++ks) {
            const int k = ks * 32;
            #pragma unroll
            for (int gt = 0; gt < 3; ++gt) {
                const short8 a = *(const short8*)(wbase + (gt * 16 + lr) * WPAD + k);
                acc[gt] = __builtin_amdgcn_mfma_f32_16x16x32_bf16(a, hv[ks].s8,
                                                                  acc[gt], 0, 0, 0);
            }
        }
        // (d) protect red: all gi-reduce reads done before rec-partial writes
        __syncthreads();
        // (e) write rec partials
        #pragma unroll
        for (int gt = 0; gt < 3; ++gt)
            #pragma unroll
            for (int q = 0; q < 4; ++q)
                red[kq][gt * 16 + lq * 4 + q][lr] = acc[gt][q];   // row=lq*4+q, col=lr
        __syncthreads();

        // (f) gates + h update
        const float ghr = red[0][u][bl]      + red[1][u][bl]
                        + red[2][u][bl]      + red[3][u][bl];
        const float ghi = red[0][16 + u][bl] + red[1][16 + u][bl]
                        + red[2][16 + u][bl] + red[3][16 + u][bl];
        const float ghn = red[0][32 + u][bl] + red[1][32 + u][bl]
                        + red[2][32 + u][bl] + red[3][32 + u][bl];
        const float rr = sigmoidf_(gir + ghr + bhr);
        const float zz = sigmoidf_(gii + ghi + bhi);
        const float nn = tanhf_(gin + rr * (ghn + bhn));
        h_reg = zz * nn + (1.f - zz) * h_reg;

        // packed pair store (u, u^1 share one dword), write-through sc1
        unsigned int hvv = (unsigned int)f2bf(h_reg);
        unsigned int ovv = __shfl_xor((int)hvv, 1);
        if ((u & 1) == 0)
            __hip_atomic_store((unsigned int*)&hwr[b * RNN + j],
                               hvv | (ovv << 16), __ATOMIC_RELAXED,
                               __HIP_MEMORY_SCOPE_AGENT);

        // (g) arrive; (h,i) gi(t+1) under the spin window; (j) wait
        gbar_arrive(lines, lid, (unsigned)(pbase + 2 + t));
        const int tn = (t + 1 < nsteps) ? t + 1 : t;
        gi_compute(t0 + tn);
        gbar_wait(lines, (unsigned)(pbase + 2 + t));
    }
    hf[b * RNN + j] = h_reg;
}

// ============================================================================
// K3: out[b,o] = h_last[b,:] . fc_w[o,:] + fc_b[o]
// ============================================================================
__global__ __launch_bounds__(256) void out_kernel(
    const float* __restrict__ hf, const float* __restrict__ fc_w,
    const float* __restrict__ fc_b, float* __restrict__ out)
{
    __shared__ float red[256];
    const int bidx = blockIdx.x, tid = threadIdx.x;
    const int o = tid & 3, seg = tid >> 2;
    const float* hp = hf   + (size_t)bidx * RNN + seg * 16;
    const float* wp = fc_w + (size_t)o * RNN + seg * 16;
    float acc = 0.f;
    #pragma unroll
    for (int i = 0; i < 16; ++i) acc += hp[i] * wp[i];
    red[tid] = acc;
    __syncthreads();
    if (tid < 4) {
        float sv = fc_b[tid];
        #pragma unroll 8
        for (int q = 0; q < 64; ++q) sv += red[q * 4 + tid];
        out[bidx * 4 + tid] = sv;
    }
}

extern "C" void kernel_launch(void* const* d_in, const int* in_sizes, int n_in,
                              void* d_out, int out_size, void* d_ws, size_t ws_size,
                              hipStream_t stream)
{
    const int*   x     = (const int*)d_in[0];
    const float* emb   = (const float*)d_in[1];
    const float* w_ih  = (const float*)d_in[2];
    const float* w_hh  = (const float*)d_in[3];
    const float* b_ih  = (const float*)d_in[4];
    const float* b_hh  = (const float*)d_in[5];
    const float* fc_w  = (const float*)d_in[6];
    const float* fc_b  = (const float*)d_in[7];
    float*       out   = (float*)d_out;

    // Workspace: h buffers + bar (+ emb bf16 copy if room). No gi buffer.
    const size_t bar_b   = (size_t)NGRP * 256 * 4;
    const size_t base_b  = 2 * (size_t)BATCH * RNN * 2
                         + (size_t)BATCH * RNN * 4 + bar_b;
    const size_t embbf_b = (size_t)VOCAB * EMB * 2;
    const bool bfpath = ws_size >= base_b + embbf_b;

    char* ws = (char*)d_ws;
    size_t off = 0;
    unsigned short* hb0 = (unsigned short*)(ws + off); off += (size_t)BATCH * RNN * 2;
    unsigned short* hb1 = (unsigned short*)(ws + off); off += (size_t)BATCH * RNN * 2;
    float*          hf  = (float*)(ws + off);          off += (size_t)BATCH * RNN * 4;
    unsigned int*   bar = (unsigned int*)(ws + off);   off += bar_b;
    unsigned short* embbf = (unsigned short*)(ws + off);

    hipFuncSetAttribute((const void*)rec_kernel<true>,
                        hipFuncAttributeMaxDynamicSharedMemorySize, REC_SMEM);
    hipFuncSetAttribute((const void*)rec_kernel<false>,
                        hipFuncAttributeMaxDynamicSharedMemorySize, REC_SMEM);

    bar_init<<<dim3(1), dim3(256), 0, stream>>>(bar);
    if (bfpath)
        cvt_bf16_kernel<<<dim3((VOCAB * EMB / 8 + 255) / 256), dim3(256), 0, stream>>>(
            emb, embbf, VOCAB * EMB / 8);

    int t0 = 0, ns = T_TOTAL, pb = 0;
    const void* embp = bfpath ? (const void*)embbf : (const void*)emb;
    void* args[13];
    args[0]  = (void*)&x;    args[1]  = (void*)&embp;  args[2]  = (void*)&w_ih;
    args[3]  = (void*)&b_ih; args[4]  = (void*)&w_hh;  args[5]  = (void*)&b_hh;
    args[6]  = (void*)&hb0;  args[7]  = (void*)&hb1;   args[8]  = (void*)&hf;
    args[9]  = (void*)&bar;  args[10] = (void*)&t0;    args[11] = (void*)&ns;
    args[12] = (void*)&pb;
    if (bfpath)
        hipLaunchCooperativeKernel((const void*)rec_kernel<true>, dim3(NWG), dim3(256),
                                   args, REC_SMEM, stream);
    else
        hipLaunchCooperativeKernel((const void*)rec_kernel<false>, dim3(NWG), dim3(256),
                                   args, REC_SMEM, stream);
    out_kernel<<<dim3(BATCH), dim3(256), 0, stream>>>(hf, fc_w, fc_b, out);
}

// Round 8
// 1915.818 us; speedup vs baseline: 1.1625x; 1.1625x over previous
//
#include <hip/hip_runtime.h>
#include <hip/hip_bf16.h>

typedef __attribute__((ext_vector_type(8))) short  short8;   // 8 bf16 (4 VGPRs) MFMA frag
typedef __attribute__((ext_vector_type(4))) float  f32x4;    // MFMA accum frag

#define T_TOTAL 512
#define BATCH   64
#define VOCAB   32000
#define EMB     512
#define RNN     1024
#define G3      3072      // 3*RNN
#define WROWS   48        // 3 gates x 16 units per WG
#define WPAD    1032      // w_hh LDS row stride (shorts): 2-way bank alias (free, proven)
#define RPAD    18        // red[] batch stride (floats): max 2-way (free)
#define NWG     256
#define NGRP    4         // independent batch groups (16 batches each)
#define NLINE   2         // arrival lines per group (32 WGs each)
// LDS: w_hh 48*1032*2=99072 | red 4*48*18*4=13824 -> 112896 (R0-proven size)
#define REC_SMEM (WROWS * WPAD * 2 + 4 * WROWS * RPAD * 4)

// ---- bf16 helpers ----
__device__ __forceinline__ unsigned short f2bf(float f) {
    union { float f; unsigned int u; } v; v.f = f;
    unsigned int r = v.u + 0x7fffu + ((v.u >> 16) & 1u);   // round-nearest-even
    return (unsigned short)(r >> 16);
}
__device__ __forceinline__ float bf2f(unsigned short h) {
    union { unsigned int u; float f; } v; v.u = ((unsigned int)h) << 16;
    return v.f;
}
__device__ __forceinline__ float sigmoidf_(float x) { return 1.f / (1.f + __expf(-x)); }
__device__ __forceinline__ float tanhf_(float x) {
    float ax = fabsf(x);
    float e2 = __expf(-2.f * ax);
    float t  = (1.f - e2) / (1.f + e2);
    return x < 0.f ? -t : t;
}

// ============================================================================
// R0/R7 barrier (best measured, VERBATIM): split-phase per-group.
// ============================================================================
__device__ __forceinline__ void gbar_arrive(unsigned int* lines, int lid,
                                            unsigned int ph) {
    __syncthreads();                         // all waves' h stores drained (vmcnt 0)
    if (threadIdx.x == 0)
        __hip_atomic_fetch_add(&lines[lid * 64], 1u,
                               __ATOMIC_RELAXED, __HIP_MEMORY_SCOPE_AGENT);
}
__device__ __forceinline__ void gbar_wait(unsigned int* lines, unsigned int ph) {
    if (threadIdx.x < NLINE) {               // lanes 0,1 of wave 0, exec-masked spin
        while (__hip_atomic_load(&lines[threadIdx.x * 64], __ATOMIC_RELAXED,
                                 __HIP_MEMORY_SCOPE_AGENT) < ph * 32u)
            __builtin_amdgcn_s_sleep(1);
    }
    __syncthreads();
}

__global__ void bar_init(unsigned int* bar) {
    for (int i = threadIdx.x; i < NGRP * 256; i += 256) bar[i] = 0;
}

// f32 -> bf16 pre-convert (8 elems/thread). One-shot per launch; BW-bound.
__global__ __launch_bounds__(256) void cvt_bf16_kernel(
    const float* __restrict__ s, unsigned short* __restrict__ d, int n8)
{
    const int i = blockIdx.x * 256 + threadIdx.x;
    if (i >= n8) return;
    const float4 a = ((const float4*)s)[i * 2];
    const float4 b = ((const float4*)s)[i * 2 + 1];
    short8 v;
    v[0] = f2bf(a.x); v[1] = f2bf(a.y); v[2] = f2bf(a.z); v[3] = f2bf(a.w);
    v[4] = f2bf(b.x); v[5] = f2bf(b.y); v[6] = f2bf(b.z); v[7] = f2bf(b.w);
    ((short8*)d)[i] = v;
}

// ============================================================================
// K2: recurrence with FUSED gi, leak-free schedule (vs R7):
//  - w_ih fragments live in 48 VGPRs/lane (loaded once at init; no Wih LDS,
//    no per-step LDS A-reads, no added bank conflicts; LDS back to 112896).
//  - the x -> emb gather chain for step t+1 is ISSUED EARLY (x at step top,
//    emb right after the h loads) so its latency hides under rec compute;
//    the post-arrive phase is 12 register-only MFMAs + red writes.
// Everything else verbatim R0/R7.
// ============================================================================
template<bool BF>
__global__ __launch_bounds__(256, 1) void rec_kernel(
    const int* __restrict__ x, const void* __restrict__ embp,
    const float* __restrict__ w_ih, const float* __restrict__ b_ih,
    const float* __restrict__ w_hh, const float* __restrict__ b_hh,
    unsigned short* __restrict__ hb0, unsigned short* __restrict__ hb1,
    float* __restrict__ hf, unsigned int* bar, int t0, int nsteps, int pbase)
{
    extern __shared__ __align__(16) char smem[];
    unsigned short* Wsm = (unsigned short*)smem;                       // 48 x WPAD
    float (*red)[WROWS][RPAD] = (float (*)[WROWS][RPAD])(smem + WROWS * WPAD * 2);

    const int tid = threadIdx.x;
    const int wg  = blockIdx.x;
    const int grp = wg & 3, sidx = wg >> 2;
    const int b0 = grp * 16, j0 = sidx * 16;
    unsigned int* lines = &bar[grp * 256];          // 2 lines, 256B apart
    const int lid = sidx & (NLINE - 1);

    // ---- stage w_hh slice -> LDS bf16 (rows: [gate*16+u][k]) ----
    #pragma unroll 4
    for (int it = 0; it < 48; ++it) {
        const int i   = it * 256 + tid;
        const int row = i >> 8;                     // 0..47 (256 float4 per row)
        const int c4  = (i & 255) * 4;
        const int gate = row >> 4, uu = row & 15;
        const float4 v = *(const float4*)(w_hh + (size_t)(gate * RNN + j0 + uu) * RNN + c4);
        unsigned short* dst = &Wsm[row * WPAD + c4];
        dst[0] = f2bf(v.x); dst[1] = f2bf(v.y); dst[2] = f2bf(v.z); dst[3] = f2bf(v.w);
    }

    // ---- MFMA identity: wave kq = K quarter; lr = batch col / unit row ----
    const int lane = tid & 63, kq = tid >> 6;
    const int lr = lane & 15, lq = lane >> 4;

    // ---- w_ih A-fragments -> registers (static all steps; 48 VGPRs) ----
    // gate gt, unit j0+lr, cols kq*128 + ks*32 + lq*8 .. +8  (gi K=512 split 4 ways)
    short8 wihf[3][4];
    #pragma unroll
    for (int gt = 0; gt < 3; ++gt) {
        const float* srow = w_ih + (size_t)(gt * RNN + j0 + lr) * EMB
                          + kq * 128 + lq * 8;
        #pragma unroll
        for (int ks = 0; ks < 4; ++ks) {
            const float4 s0 = *(const float4*)(srow + ks * 32);
            const float4 s1 = *(const float4*)(srow + ks * 32 + 4);
            short8 w;
            w[0]=f2bf(s0.x); w[1]=f2bf(s0.y); w[2]=f2bf(s0.z); w[3]=f2bf(s0.w);
            w[4]=f2bf(s1.x); w[5]=f2bf(s1.y); w[6]=f2bf(s1.z); w[7]=f2bf(s1.w);
            wihf[gt][ks] = w;
        }
    }

    // ---- gate-thread identity: (unit u 0..15, batch bl 0..15) ----
    const int u  = tid & 15;
    const int bl = tid >> 4;
    const int j  = j0 + u;
    const int b  = b0 + bl;
    const float bhr  = b_hh[j], bhi  = b_hh[RNN + j], bhn  = b_hh[2 * RNN + j];
    const float bihr = b_ih[j], bihi = b_ih[RNN + j], bihn = b_ih[2 * RNN + j];

    float h_reg;
    if (t0 == 0) {
        h_reg = 0.f;
        if ((u & 1) == 0)
            __hip_atomic_store((unsigned int*)&hb0[b * RNN + j], 0u,
                               __ATOMIC_RELAXED, __HIP_MEMORY_SCOPE_AGENT);
    } else {
        h_reg = hf[b * RNN + j];            // f32 state from previous launch
    }
    gbar_arrive(lines, lid, (unsigned)(pbase + 1));   // sync also covers LDS staging

    const unsigned short* wbase = Wsm + kq * 256 + lq * 8;            // w_hh: K/4=256
    const size_t hoff = ((size_t)(b0 + lr) * RNN + kq * 256 + lq * 8) >> 2;  // in u64s

    // ---- gi helpers ----
    auto gi_load = [&](int tg, short8* bfr) {
        const int xi = x[tg * BATCH + b0 + lr];     // gather index for batch col lr
        if constexpr (BF) {
            const unsigned short* erow = (const unsigned short*)embp
                                       + (size_t)xi * EMB + kq * 128 + lq * 8;
            #pragma unroll
            for (int ks = 0; ks < 4; ++ks)
                bfr[ks] = *(const short8*)(erow + ks * 32);
        } else {
            const float* erow = (const float*)embp
                              + (size_t)xi * EMB + kq * 128 + lq * 8;
            #pragma unroll
            for (int ks = 0; ks < 4; ++ks) {
                const float4 e0 = *(const float4*)(erow + ks * 32);
                const float4 e1 = *(const float4*)(erow + ks * 32 + 4);
                short8 v;
                v[0]=f2bf(e0.x); v[1]=f2bf(e0.y); v[2]=f2bf(e0.z); v[3]=f2bf(e0.w);
                v[4]=f2bf(e1.x); v[5]=f2bf(e1.y); v[6]=f2bf(e1.z); v[7]=f2bf(e1.w);
                bfr[ks] = v;
            }
        }
    };
    auto gi_mfma = [&](const short8* bfr) {          // register-only + red writes
        f32x4 acc2[3];
        acc2[0] = (f32x4){0.f, 0.f, 0.f, 0.f};
        acc2[1] = (f32x4){0.f, 0.f, 0.f, 0.f};
        acc2[2] = (f32x4){0.f, 0.f, 0.f, 0.f};
        #pragma unroll
        for (int ks = 0; ks < 4; ++ks)
            #pragma unroll
            for (int gt = 0; gt < 3; ++gt)
                acc2[gt] = __builtin_amdgcn_mfma_f32_16x16x32_bf16(
                    wihf[gt][ks], bfr[ks], acc2[gt], 0, 0, 0);
        #pragma unroll
        for (int gt = 0; gt < 3; ++gt)
            #pragma unroll
            for (int q = 0; q < 4; ++q)
                red[kq][gt * 16 + lq * 4 + q][lr] = acc2[gt][q];   // row=lq*4+q, col=lr
    };

    // gi(t0) under the initial barrier spin window
    short8 bfr[4];
    gi_load(t0, bfr);
    gi_mfma(bfr);
    gbar_wait(lines, (unsigned)(pbase + 1));   // release; red (gi partials) visible

    for (int t = 0; t < nsteps; ++t) {
        // (a) gi-reduce for this step (+ input bias)
        const float gir = red[0][u][bl]      + red[1][u][bl]
                        + red[2][u][bl]      + red[3][u][bl]      + bihr;
        const float gii = red[0][16 + u][bl] + red[1][16 + u][bl]
                        + red[2][16 + u][bl] + red[3][16 + u][bl] + bihi;
        const float gin = red[0][32 + u][bl] + red[1][32 + u][bl]
                        + red[2][32 + u][bl] + red[3][32 + u][bl] + bihn;

        const unsigned short* hrd = (t & 1) ? hb1 : hb0;
        unsigned short*       hwr = (t & 1) ? hb0 : hb1;

        // (b) h loads (MALL) ... then (b2) gi(t+1) gather issued EARLY:
        // its x->emb latency hides under rec MFMAs + gates + arrive.
        union { unsigned long long q[2]; short8 s8; } hv[8];
        const unsigned long long* hp = (const unsigned long long*)hrd + hoff;
        #pragma unroll
        for (int ks = 0; ks < 8; ++ks) {
            hv[ks].q[0] = __hip_atomic_load(hp + ks * 8,     __ATOMIC_RELAXED,
                                            __HIP_MEMORY_SCOPE_AGENT);
            hv[ks].q[1] = __hip_atomic_load(hp + ks * 8 + 1, __ATOMIC_RELAXED,
                                            __HIP_MEMORY_SCOPE_AGENT);
        }
        const int tn = (t + 1 < nsteps) ? t + 1 : t;
        gi_load(t0 + tn, bfr);                        // issue; consumed at (h)

        // (c) rec MFMAs
        f32x4 acc[3];
        acc[0] = (f32x4){0.f, 0.f, 0.f, 0.f};
        acc[1] = (f32x4){0.f, 0.f, 0.f, 0.f};
        acc[2] = (f32x4){0.f, 0.f, 0.f, 0.f};
        #pragma unroll
        for (int ks = 0; ks < 8; ++ks) {
            const int k = ks * 32;
            #pragma unroll
            for (int gt = 0; gt < 3; ++gt) {
                const short8 a = *(const short8*)(wbase + (gt * 16 + lr) * WPAD + k);
                acc[gt] = __builtin_amdgcn_mfma_f32_16x16x32_bf16(a, hv[ks].s8,
                                                                  acc[gt], 0, 0, 0);
            }
        }
        // (d) protect red: all gi-reduce reads done before rec-partial writes
        __syncthreads();
        // (e) write rec partials
        #pragma unroll
        for (int gt = 0; gt < 3; ++gt)
            #pragma unroll
            for (int q = 0; q < 4; ++q)
                red[kq][gt * 16 + lq * 4 + q][lr] = acc[gt][q];   // row=lq*4+q, col=lr
        __syncthreads();

        // (f) gates + h update
        const float ghr = red[0][u][bl]      + red[1][u][bl]
                        + red[2][u][bl]      + red[3][u][bl];
        const float ghi = red[0][16 + u][bl] + red[1][16 + u][bl]
                        + red[2][16 + u][bl] + red[3][16 + u][bl];
        const float ghn = red[0][32 + u][bl] + red[1][32 + u][bl]
                        + red[2][32 + u][bl] + red[3][32 + u][bl];
        const float rr = sigmoidf_(gir + ghr + bhr);
        const float zz = sigmoidf_(gii + ghi + bhi);
        const float nn = tanhf_(gin + rr * (ghn + bhn));
        h_reg = zz * nn + (1.f - zz) * h_reg;

        // packed pair store (u, u^1 share one dword), write-through sc1
        unsigned int hvv = (unsigned int)f2bf(h_reg);
        unsigned int ovv = __shfl_xor((int)hvv, 1);
        if ((u & 1) == 0)
            __hip_atomic_store((unsigned int*)&hwr[b * RNN + j],
                               hvv | (ovv << 16), __ATOMIC_RELAXED,
                               __HIP_MEMORY_SCOPE_AGENT);

        // (g) arrive; (h) register-only gi MFMAs under the spin; (j) wait
        gbar_arrive(lines, lid, (unsigned)(pbase + 2 + t));
        gi_mfma(bfr);
        gbar_wait(lines, (unsigned)(pbase + 2 + t));
    }
    hf[b * RNN + j] = h_reg;
}

// ============================================================================
// K3: out[b,o] = h_last[b,:] . fc_w[o,:] + fc_b[o]
// ============================================================================
__global__ __launch_bounds__(256) void out_kernel(
    const float* __restrict__ hf, const float* __restrict__ fc_w,
    const float* __restrict__ fc_b, float* __restrict__ out)
{
    __shared__ float red[256];
    const int bidx = blockIdx.x, tid = threadIdx.x;
    const int o = tid & 3, seg = tid >> 2;
    const float* hp = hf   + (size_t)bidx * RNN + seg * 16;
    const float* wp = fc_w + (size_t)o * RNN + seg * 16;
    float acc = 0.f;
    #pragma unroll
    for (int i = 0; i < 16; ++i) acc += hp[i] * wp[i];
    red[tid] = acc;
    __syncthreads();
    if (tid < 4) {
        float sv = fc_b[tid];
        #pragma unroll 8
        for (int q = 0; q < 64; ++q) sv += red[q * 4 + tid];
        out[bidx * 4 + tid] = sv;
    }
}

extern "C" void kernel_launch(void* const* d_in, const int* in_sizes, int n_in,
                              void* d_out, int out_size, void* d_ws, size_t ws_size,
                              hipStream_t stream)
{
    const int*   x     = (const int*)d_in[0];
    const float* emb   = (const float*)d_in[1];
    const float* w_ih  = (const float*)d_in[2];
    const float* w_hh  = (const float*)d_in[3];
    const float* b_ih  = (const float*)d_in[4];
    const float* b_hh  = (const float*)d_in[5];
    const float* fc_w  = (const float*)d_in[6];
    const float* fc_b  = (const float*)d_in[7];
    float*       out   = (float*)d_out;

    // Workspace: h buffers + bar (+ emb bf16 copy if room). No gi buffer.
    const size_t bar_b   = (size_t)NGRP * 256 * 4;
    const size_t base_b  = 2 * (size_t)BATCH * RNN * 2
                         + (size_t)BATCH * RNN * 4 + bar_b;
    const size_t embbf_b = (size_t)VOCAB * EMB * 2;
    const bool bfpath = ws_size >= base_b + embbf_b;

    char* ws = (char*)d_ws;
    size_t off = 0;
    unsigned short* hb0 = (unsigned short*)(ws + off); off += (size_t)BATCH * RNN * 2;
    unsigned short* hb1 = (unsigned short*)(ws + off); off += (size_t)BATCH * RNN * 2;
    float*          hf  = (float*)(ws + off);          off += (size_t)BATCH * RNN * 4;
    unsigned int*   bar = (unsigned int*)(ws + off);   off += bar_b;
    unsigned short* embbf = (unsigned short*)(ws + off);

    hipFuncSetAttribute((const void*)rec_kernel<true>,
                        hipFuncAttributeMaxDynamicSharedMemorySize, REC_SMEM);
    hipFuncSetAttribute((const void*)rec_kernel<false>,
                        hipFuncAttributeMaxDynamicSharedMemorySize, REC_SMEM);

    bar_init<<<dim3(1), dim3(256), 0, stream>>>(bar);
    if (bfpath)
        cvt_bf16_kernel<<<dim3((VOCAB * EMB / 8 + 255) / 256), dim3(256), 0, stream>>>(
            emb, embbf, VOCAB * EMB / 8);

    int t0 = 0, ns = T_TOTAL, pb = 0;
    const void* embp = bfpath ? (const void*)embbf : (const void*)emb;
    void* args[13];
    args[0]  = (void*)&x;    args[1]  = (void*)&embp;  args[2]  = (void*)&w_ih;
    args[3]  = (void*)&b_ih; args[4]  = (void*)&w_hh;  args[5]  = (void*)&b_hh;
    args[6]  = (void*)&hb0;  args[7]  = (void*)&hb1;   args[8]  = (void*)&hf;
    args[9]  = (void*)&bar;  args[10] = (void*)&t0;    args[11] = (void*)&ns;
    args[12] = (void*)&pb;
    if (bfpath)
        hipLaunchCooperativeKernel((const void*)rec_kernel<true>, dim3(NWG), dim3(256),
                                   args, REC_SMEM, stream);
    else
        hipLaunchCooperativeKernel((const void*)rec_kernel<false>, dim3(NWG), dim3(256),
                                   args, REC_SMEM, stream);
    out_kernel<<<dim3(BATCH), dim3(256), 0, stream>>>(hf, fc_w, fc_b, out);
}